// Round 5
// baseline (363.665 us; speedup 1.0000x reference)
//
#include <hip/hip_runtime.h>
#include <hip/hip_bf16.h>
#include <cmath>

#define BN_EPS 1e-6f
typedef unsigned int u32;
typedef __attribute__((ext_vector_type(8))) short short8;   // 8 bf16 (4 VGPRs)
typedef __attribute__((ext_vector_type(4))) float f32x4;    // MFMA accum

constexpr int B_    = 4;
constexpr int N_    = 16384;
constexpr int K_    = 16;
constexpr int C_IMG = 54;
constexpr int C1    = 64;     // concat channels (permuted: [imgf 54 | computed 10])
constexpr int CO    = 32;
constexpr int C2    = 70;
constexpr int NK    = N_ * K_;

constexpr int NTB   = 64;     // n per block
constexpr int NSTEP = 8;      // steps per block
constexpr int SPOS  = 128;    // positions per step (8 n x 16 k)
constexpr int XR    = 132;    // xbuf row stride (u32): 128 + 4 pad
constexpr int XBUFB = 27 * XR * 4;   // byte stride between xbuf buffers (14256)
constexpr int CST   = 1028;   // comp_lds row stride (u32)
constexpr int PST   = 73;     // pooled_all row stride (f32): 73 odd -> epilogue 2-way (free)
constexpr int TPB   = N_ / NTB;            // 256 tiles per batch
constexpr int NBLK  = B_ * TPB;            // 1024 blocks = 8 XCD * 128

__device__ inline u32 pkbf(float a, float b) {      // pack 2 fp32 -> 2 bf16 (RNE), a low
    union { __hip_bfloat162 h; u32 u; } cv;
    cv.h = __float22bfloat162_rn(make_float2(a, b));
    return cv.u;
}

// R5: leak-free depth-2 persistent pipeline.
//  - steady loop VMEM = ONLY the 8 staged imgf loads/wave/step (uniform count ->
//    counted vmcnt(8), never drained); one raw s_barrier + lgkmcnt(0) per step.
//  - reg pipeline: issue loads(s+2) -> {rA|rB by parity}; pack loads(s+1) -> xbuf[(s+1)&1].
//  - all idx/dist/points + ep + W1 frags in prologue; conv2 in epilogue.
__global__ __launch_bounds__(256, 2) void pif_mfma_kernel(
    const float* __restrict__ points, const float* __restrict__ imgf,
    const float* __restrict__ dist,   const int*   __restrict__ idx,
    const float* __restrict__ w1, const float* __restrict__ b1,
    const float* __restrict__ g1, const float* __restrict__ be1,
    const float* __restrict__ m1, const float* __restrict__ v1,
    const float* __restrict__ w2, const float* __restrict__ b2,
    const float* __restrict__ g2, const float* __restrict__ be2,
    const float* __restrict__ m2, const float* __restrict__ v2,
    float* __restrict__ out)
{
    __shared__ __align__(16) u32 xbuf[2][27][XR];      // 28512 B (bf16 ch-pairs, [cp][pos])
    __shared__ u32   comp_lds[5][CST];                 // 20560 B (computed ch-pairs, whole block)
    __shared__ float pooled_all[NTB][PST];             // 18688 B (total 67760 -> 2 blocks/CU)

    const int t = threadIdx.x;
    const int g = blockIdx.x;
    const int sw  = (g & 7) * (NBLK / 8) + (g >> 3);   // bijective XCD swizzle
    const int b   = sw / TPB;
    const int bn0 = (sw % TPB) * NTB;

    const int lane = t & 63, w = t >> 6;
    const int m16 = lane & 15, quad = lane >> 4;

    // ---- staging map: 864 items/step = 4 waves x 216; 8 load-instrs/wave/step ----
    const float* ib = imgf + (size_t)b * C_IMG * NK + bn0 * K_;
    const float* gp0[4]; const float* gp1[4]; u32* lw[4];
    #pragma unroll
    for (int jj = 0; jj < 4; ++jj) {
        const int item = w * 216 + ((jj < 3) ? jj * 64 + lane : 192 + lane);
        const int cp = item >> 5, q = item & 31;
        gp0[jj] = ib + (size_t)(2 * cp) * NK + 4 * q;
        gp1[jj] = ib + (size_t)(2 * cp + 1) * NK + 4 * q;
        lw[jj]  = &xbuf[0][cp][4 * q];
    }

    float4 rA[4][2], rB[4][2];
    // issue steps 0,1 immediately
    #pragma unroll
    for (int jj = 0; jj < 4; ++jj)
        if (jj < 3 || lane < 24) {
            rA[jj][0] = *(const float4*)(gp0[jj]);
            rA[jj][1] = *(const float4*)(gp1[jj]);
        }
    #pragma unroll
    for (int jj = 0; jj < 4; ++jj)
        if (jj < 3 || lane < 24) {
            rB[jj][0] = *(const float4*)(gp0[jj] + SPOS);
            rB[jj][1] = *(const float4*)(gp1[jj] + SPOS);
        }

    // ---- prologue: computed channels for all 1024 pos ----
    #pragma unroll
    for (int c2 = 0; c2 < 4; ++c2) {
        const int pos = c2 * 256 + t;
        const int nl = pos >> 4, kk = pos & 15;
        const int gn = bn0 + nl;
        const int ii = (b * N_ + gn) * K_ + kk;
        const int jx = idx[ii];
        const float dvv = dist[ii];
        const int pbo = (b * N_ + gn) * 3;
        const float px = points[pbo], py = points[pbo + 1], pz = points[pbo + 2];
        const int qbo = (b * N_ + jx) * 3;
        const float qx = points[qbo], qy = points[qbo + 1], qz = points[qbo + 2];
        comp_lds[0][pos] = pkbf(px, py);
        comp_lds[1][pos] = pkbf(pz, qx);
        comp_lds[2][pos] = pkbf(qy, qz);
        comp_lds[3][pos] = pkbf(px - qx, py - qy);
        comp_lds[4][pos] = pkbf(pz - qz, dvv);
    }
    // ep rows of pooled (max == mean == value), whole block
    if (t < 192) {
        const int nn = t & 63, jj = t >> 6;
        const float v = points[(b * N_ + bn0 + nn) * 3 + jj];
        pooled_all[nn][32 + jj] = v;
        pooled_all[nn][67 + jj] = v;
    }

    // B-frags, permuted: logical c<54 -> w1 col 10+c ; c>=54 -> col c-54
    short8 bfrag[2][2];
    float  inv1v[2], add1v[2];
    #pragma unroll
    for (int ot = 0; ot < 2; ++ot) {
        const int o = ot * 16 + m16;
        #pragma unroll
        for (int kc = 0; kc < 2; ++kc) {
            union { u32 u[4]; short8 v; } bf;
            #pragma unroll
            for (int i2 = 0; i2 < 4; ++i2) {
                const int lc0 = kc * 32 + quad * 8 + 2 * i2, lc1 = lc0 + 1;
                const int c0 = (lc0 < 54) ? (10 + lc0) : (lc0 - 54);
                const int c1 = (lc1 < 54) ? (10 + lc1) : (lc1 - 54);
                bf.u[i2] = pkbf(w1[o * C1 + c0], w1[o * C1 + c1]);
            }
            bfrag[ot][kc] = bf.v;
        }
        const float iv = g1[o] * rsqrtf(v1[o] + BN_EPS);
        inv1v[ot] = iv;
        add1v[ot] = be1[o] - m1[o] * iv + b1[o] * iv;
    }

    // pack step 0 -> xbuf[0] (compiler inserts the vmcnt wait for rA)
    #pragma unroll
    for (int jj = 0; jj < 4; ++jj)
        if (jj < 3 || lane < 24) {
            uint4 pk;
            pk.x = pkbf(rA[jj][0].x, rA[jj][1].x);
            pk.y = pkbf(rA[jj][0].y, rA[jj][1].y);
            pk.z = pkbf(rA[jj][0].z, rA[jj][1].z);
            pk.w = pkbf(rA[jj][0].w, rA[jj][1].w);
            *(uint4*)lw[jj] = pk;
        }

    __syncthreads();   // prologue-only full drain

#define PIF_COMPUTE(S)                                                         \
    {                                                                          \
        const u32* Xi = &xbuf[(S) & 1][0][0];                                  \
        _Pragma("unroll")                                                      \
        for (int u = 0; u < 2; ++u) {                                          \
            const int m = 2 * w + u;                                           \
            const int p = m * 16 + m16;                                        \
            f32x4 acc0 = (f32x4){0.f, 0.f, 0.f, 0.f};                          \
            f32x4 acc1 = (f32x4){0.f, 0.f, 0.f, 0.f};                          \
            {                                                                  \
                union { u32 uu[4]; short8 v; } af;                             \
                _Pragma("unroll")                                              \
                for (int i2 = 0; i2 < 4; ++i2)                                 \
                    af.uu[i2] = Xi[(quad * 4 + i2) * XR + p];                   \
                acc0 = __builtin_amdgcn_mfma_f32_16x16x32_bf16(af.v, bfrag[0][0], acc0, 0, 0, 0); \
                acc1 = __builtin_amdgcn_mfma_f32_16x16x32_bf16(af.v, bfrag[1][0], acc1, 0, 0, 0); \
            }                                                                  \
            {                                                                  \
                union { u32 uu[4]; short8 v; } af;                             \
                if (quad < 2) {                                                \
                    _Pragma("unroll")                                          \
                    for (int i2 = 0; i2 < 4; ++i2)                             \
                        af.uu[i2] = Xi[(16 + quad * 4 + i2) * XR + p];          \
                } else if (quad == 2) {                                        \
                    _Pragma("unroll")                                          \
                    for (int i2 = 0; i2 < 3; ++i2)                             \
                        af.uu[i2] = Xi[(24 + i2) * XR + p];                     \
                    af.uu[3] = comp_lds[0][(S) * SPOS + p];                    \
                } else {                                                       \
                    _Pragma("unroll")                                          \
                    for (int i2 = 0; i2 < 4; ++i2)                             \
                        af.uu[i2] = comp_lds[1 + i2][(S) * SPOS + p];          \
                }                                                              \
                acc0 = __builtin_amdgcn_mfma_f32_16x16x32_bf16(af.v, bfrag[0][1], acc0, 0, 0, 0); \
                acc1 = __builtin_amdgcn_mfma_f32_16x16x32_bf16(af.v, bfrag[1][1], acc1, 0, 0, 0); \
            }                                                                  \
            _Pragma("unroll")                                                  \
            for (int ot = 0; ot < 2; ++ot) {                                   \
                const f32x4 aa = ot ? acc1 : acc0;                             \
                float mx = 0.f, sm = 0.f;                                      \
                _Pragma("unroll")                                              \
                for (int r = 0; r < 4; ++r) {                                  \
                    float hv = fmaf(aa[r], inv1v[ot], add1v[ot]);              \
                    hv = fmaxf(hv, 0.f);                                       \
                    mx = fmaxf(mx, hv);                                        \
                    sm += hv;                                                  \
                }                                                              \
                mx = fmaxf(mx, __shfl_xor(mx, 16));                            \
                mx = fmaxf(mx, __shfl_xor(mx, 32));                            \
                sm += __shfl_xor(sm, 16);                                      \
                sm += __shfl_xor(sm, 32);                                      \
                if (quad == 0) {                                               \
                    pooled_all[(S) * 8 + m][ot * 16 + m16]      = mx;          \
                    pooled_all[(S) * 8 + m][35 + ot * 16 + m16] = sm * (1.f / 16.f); \
                }                                                              \
            }                                                                  \
        }                                                                      \
    }

#define PIF_STEP(S, RISS, RPK)                                                 \
    {                                                                          \
        if ((S) + 2 < NSTEP) {                                                 \
            _Pragma("unroll")                                                  \
            for (int jj = 0; jj < 4; ++jj)                                     \
                if (jj < 3 || lane < 24) {                                     \
                    RISS[jj][0] = *(const float4*)(gp0[jj] + ((S) + 2) * SPOS);\
                    RISS[jj][1] = *(const float4*)(gp1[jj] + ((S) + 2) * SPOS);\
                }                                                              \
            asm volatile("s_waitcnt vmcnt(8)" ::: "memory");                   \
        } else if ((S) + 1 < NSTEP) {                                          \
            asm volatile("s_waitcnt vmcnt(0)" ::: "memory");                   \
        }                                                                      \
        if ((S) + 1 < NSTEP) {                                                 \
            _Pragma("unroll")                                                  \
            for (int jj = 0; jj < 4; ++jj)                                     \
                if (jj < 3 || lane < 24) {                                     \
                    uint4 pk;                                                  \
                    pk.x = pkbf(RPK[jj][0].x, RPK[jj][1].x);                   \
                    pk.y = pkbf(RPK[jj][0].y, RPK[jj][1].y);                   \
                    pk.z = pkbf(RPK[jj][0].z, RPK[jj][1].z);                   \
                    pk.w = pkbf(RPK[jj][0].w, RPK[jj][1].w);                   \
                    *(uint4*)((char*)lw[jj] + (((S) + 1) & 1) * XBUFB) = pk;   \
                }                                                              \
        }                                                                      \
        PIF_COMPUTE(S);                                                        \
        asm volatile("s_waitcnt lgkmcnt(0)" ::: "memory");                     \
        __builtin_amdgcn_s_barrier();                                          \
        __builtin_amdgcn_sched_barrier(0);                                     \
    }

    PIF_STEP(0, rA, rB)
    PIF_STEP(1, rB, rA)
    PIF_STEP(2, rA, rB)
    PIF_STEP(3, rB, rA)
    PIF_STEP(4, rA, rB)
    PIF_STEP(5, rB, rA)
    PIF_STEP(6, rA, rB)
    PIF_STEP(7, rB, rA)

#undef PIF_STEP
#undef PIF_COMPUTE

    // ---- epilogue: conv2 + bn2 + relu. wave w owns o in [8w, 8w+8); lane = n ----
    const int wu = __builtin_amdgcn_readfirstlane(w);
    float accE[8];
    #pragma unroll
    for (int oo = 0; oo < 8; ++oo) accE[oo] = 0.f;
    for (int c = 0; c < C2; ++c) {
        const float rv = pooled_all[lane][c];          // stride 73 -> 2-way (free)
        #pragma unroll
        for (int oo = 0; oo < 8; ++oo)
            accE[oo] = fmaf(w2[(8 * wu + oo) * C2 + c], rv, accE[oo]);  // s_load (uniform)
    }
    #pragma unroll
    for (int oo = 0; oo < 8; ++oo) {
        const int o = 8 * wu + oo;
        const float iv2 = g2[o] * rsqrtf(v2[o] + BN_EPS);
        float ov = fmaf(accE[oo] + b2[o], iv2, be2[o] - m2[o] * iv2);
        ov = fmaxf(ov, 0.f);
        out[(b * CO + o) * N_ + bn0 + lane] = ov;      // 256 B contiguous per oo
    }
}

extern "C" void kernel_launch(void* const* d_in, const int* in_sizes, int n_in,
                              void* d_out, int out_size, void* d_ws, size_t ws_size,
                              hipStream_t stream) {
    const float* points = (const float*)d_in[0];
    const float* imgf   = (const float*)d_in[1];
    const float* dist   = (const float*)d_in[2];
    const int*   idx    = (const int*)  d_in[3];
    const float* w1     = (const float*)d_in[4];
    const float* b1     = (const float*)d_in[5];
    const float* g1     = (const float*)d_in[6];
    const float* be1    = (const float*)d_in[7];
    const float* m1     = (const float*)d_in[8];
    const float* v1     = (const float*)d_in[9];
    const float* w2     = (const float*)d_in[10];
    const float* b2     = (const float*)d_in[11];
    const float* g2     = (const float*)d_in[12];
    const float* be2    = (const float*)d_in[13];
    const float* m2     = (const float*)d_in[14];
    const float* v2     = (const float*)d_in[15];
    float* out          = (float*)d_out;

    pif_mfma_kernel<<<NBLK, 256, 0, stream>>>(
        points, imgf, dist, idx,
        w1, b1, g1, be1, m1, v1,
        w2, b2, g2, be2, m2, v2, out);
}